// Round 3
// baseline (350.503 us; speedup 1.0000x reference)
//
#include <hip/hip_runtime.h>

// out[b, i*16+j, d, l] = sum_ks s[b,(j-i)&15,l,ks] * t[b,j,l,d-ks], d in [0,125); 0 for d>=125.
// B=32, N=16, L=64, D_in=63, D_out=128. Output 32*256*128*64 fp32 = 256 MB.
//
// v4: occupancy-driven restructure.
//   Post-mortem v2/v3: load coalescing +12us, store vectorization +-0. Conv sits
//   ~105us vs floors (FMA-issue 26.5us, store-BW 45us) -> latency-hiding bound at
//   3 waves/SIMD (sv63+tv63+acc16 ~ 155 VGPR). Fix: share the t-row across the
//   16 blocks that reuse it.
//   - workgroup = (b, j, half): 8 waves, one shared t-row tile in LDS (16KB).
//   - each wave: private s-row (k=(j-i)&15) in 63 regs, acc[16], kt-outer loop:
//     one conflict-free ds_read per 16 FMAs (307 total, clipped windows); sv/acc
//     indices all compile-time (no scratch).
//   - __launch_bounds__(512,4): cap 128 VGPR -> 4 waves/SIMD (+33% TLP).
//   - store: per-wave LDS transpose, row stride 68 -> aligned ds_read_b128 +
//     global_store_dwordx4 (32 store insts/wave).
//   1) transpose_kernel: s,t [B,N,L,63] -> [B,N,63,L] in d_ws so all global
//      loads are lane-coalesced. 2) conv_kernel_t2 as above.
// Fallback to the v1 uncoalesced kernel if ws_size < 16.5 MB.

#define D_IN 63
#define L_DIM 64
#define N_DIM 16
#define DP 128
#define B_DIM 32

// ---------- transpose [B,N,L,D_IN] -> [B,N,D_IN,L] ----------
__global__ __launch_bounds__(256) void transpose_kernel(
    const float* __restrict__ s, const float* __restrict__ t,
    float* __restrict__ so, float* __restrict__ to)
{
    const int tile = blockIdx.x;                     // 0..1023 ; first 512 = s, rest = t
    const int bn   = tile & (B_DIM * N_DIM - 1);     // 0..511
    const float* __restrict__ src =
        (tile < B_DIM * N_DIM ? s : t) + (size_t)bn * (L_DIM * D_IN);
    float* __restrict__ dst =
        (tile < B_DIM * N_DIM ? so : to) + (size_t)bn * (L_DIM * D_IN);

    __shared__ float lds[L_DIM * D_IN];              // 16128 B

    for (int f = threadIdx.x; f < L_DIM * D_IN; f += 256)
        lds[f] = src[f];
    __syncthreads();

    // coalesced write of the [D,L] tile; lds read stride 63 across lanes
    // (63 mod 32 = 31 -> at most 2 lanes/bank = free)
    for (int g = threadIdx.x; g < L_DIM * D_IN; g += 256) {
        const int d = g >> 6;        // 0..62
        const int l = g & 63;
        dst[g] = lds[l * D_IN + d];
    }
}

// ---------- conv: 8 waves share one t-row tile ----------
__global__ __launch_bounds__(512, 4) void conv_kernel_t2(
    const float* __restrict__ st, const float* __restrict__ tt,
    float* __restrict__ out)
{
    const int bi   = blockIdx.x;         // (b*16 + j)*2 + half
    const int half = bi & 1;
    const int j    = (bi >> 1) & 15;
    const int b    = bi >> 5;
    const int wid  = threadIdx.x >> 6;   // 0..7
    const int l    = threadIdx.x & 63;
    const int i    = half * 8 + wid;     // 0..15
    const int k    = (j - i) & 15;

    // shared t-row tile [kt][l], layout matches transposed global row (linear copy)
    __shared__ float tvt[D_IN * L_DIM];              // 16128 B
    // per-wave store-transpose tile: 8 rows x 68 (stride 68 -> aligned b128, no conflicts)
    __shared__ float xp[8][8 * 68];                  // 17408 B

    {
        const float* __restrict__ trow = tt + ((size_t)(b * N_DIM + j) * D_IN) * L_DIM;
#pragma unroll
        for (int it = 0; it < 8; ++it) {
            const int f = it * 512 + (int)threadIdx.x;
            if (f < D_IN * L_DIM) tvt[f] = trow[f];
        }
    }

    // private s-row, coalesced loads from transposed layout
    const float* __restrict__ srow = st + ((size_t)(b * N_DIM + k) * D_IN) * L_DIM + l;
    float sv[D_IN];
#pragma unroll
    for (int c = 0; c < D_IN; ++c) sv[c] = srow[(size_t)c * L_DIM];

    __syncthreads();

    const int blk = ((b * N_DIM + i) * N_DIM + j);
    float* __restrict__ obase = out + ((size_t)blk * (DP * L_DIM));
    float* __restrict__ xw = &xp[wid][0];

    const int rq = l >> 4;               // 0..3
    const int c4 = (l & 15) << 2;        // 0..60 step 4

#pragma unroll
    for (int d0 = 0; d0 < DP; d0 += 16) {
        float acc[16];
#pragma unroll
        for (int dd = 0; dd < 16; ++dd) acc[dd] = 0.0f;

        // kt window with any valid ks = d0+dd-kt in [0,63): kt in [d0-62, d0+15] clip [0,62]
        const int kt_lo = (d0 - 62 < 0) ? 0 : (d0 - 62);
        const int kt_hi = (d0 + 15 > 62) ? 62 : (d0 + 15);
#pragma unroll
        for (int kt = kt_lo; kt <= kt_hi; ++kt) {
            const float v = tvt[kt * L_DIM + l];     // 1 conflict-free ds_read / 16 FMAs
#pragma unroll
            for (int dd = 0; dd < 16; ++dd) {
                const int ks = d0 + dd - kt;         // compile-time constant
                if (ks >= 0 && ks < D_IN)
                    acc[dd] += sv[ks] * v;
            }
        }

        // store via per-wave LDS transpose: two groups of 8 d-rows
#pragma unroll
        for (int g = 0; g < 2; ++g) {
#pragma unroll
            for (int r = 0; r < 8; ++r)
                xw[r * 68 + l] = acc[g * 8 + r];
            // per-wave tile, single-wave dependency: DS ops are program-ordered.
#pragma unroll
            for (int q = 0; q < 2; ++q) {
                const int r_ = rq + (q << 2);        // 0..7
                const float4 v4 = *reinterpret_cast<const float4*>(&xw[r_ * 68 + c4]);
                *reinterpret_cast<float4*>(
                    &obase[(size_t)(d0 + g * 8 + r_) * L_DIM + c4]) = v4;
            }
        }
    }
}

// ---------- v1 fallback (uncoalesced loads) ----------
__global__ __launch_bounds__(64) void conv_kernel_fallback(
    const float* __restrict__ s, const float* __restrict__ t,
    float* __restrict__ out)
{
    const int blk = blockIdx.x;
    const int b  = blk >> 8;
    const int ij = blk & 255;
    const int i  = ij >> 4;
    const int j  = ij & 15;
    const int k  = (j - i) & 15;
    const int l  = threadIdx.x;

    const float* __restrict__ srow = s + ((((size_t)b * N_DIM + k) * L_DIM + l) * D_IN);
    const float* __restrict__ trow = t + ((((size_t)b * N_DIM + j) * L_DIM + l) * D_IN);

    float sv[D_IN], tv[D_IN];
#pragma unroll
    for (int c = 0; c < D_IN; ++c) sv[c] = srow[c];
#pragma unroll
    for (int c = 0; c < D_IN; ++c) tv[c] = trow[c];

    float* __restrict__ orow = out + ((size_t)blk * (DP * L_DIM)) + l;

#pragma unroll
    for (int d0 = 0; d0 < DP; d0 += 16) {
        float acc[16];
#pragma unroll
        for (int dd = 0; dd < 16; ++dd) acc[dd] = 0.0f;
#pragma unroll
        for (int ks = 0; ks < D_IN; ++ks) {
#pragma unroll
            for (int dd = 0; dd < 16; ++dd) {
                const int kt = d0 + dd - ks;
                if (kt >= 0 && kt < D_IN)
                    acc[dd] += sv[ks] * tv[kt];
            }
        }
#pragma unroll
        for (int dd = 0; dd < 16; ++dd)
            orow[(size_t)(d0 + dd) * L_DIM] = acc[dd];
    }
}

extern "C" void kernel_launch(void* const* d_in, const int* in_sizes, int n_in,
                              void* d_out, int out_size, void* d_ws, size_t ws_size,
                              hipStream_t stream) {
    const float* s = (const float*)d_in[0];
    const float* t = (const float*)d_in[1];
    float* out = (float*)d_out;

    const size_t elems = (size_t)B_DIM * N_DIM * L_DIM * D_IN;   // 2,064,384
    const size_t need  = 2 * elems * sizeof(float);              // ~16.5 MB

    if (d_ws != nullptr && ws_size >= need) {
        float* so = (float*)d_ws;
        float* to = so + elems;
        hipLaunchKernelGGL(transpose_kernel, dim3(2 * B_DIM * N_DIM), dim3(256), 0, stream,
                           s, t, so, to);
        // grid: (b, j, half) = 32*16*2 = 1024 workgroups x 512 threads
        hipLaunchKernelGGL(conv_kernel_t2, dim3(B_DIM * N_DIM * 2), dim3(512), 0, stream,
                           so, to, out);
    } else {
        hipLaunchKernelGGL(conv_kernel_fallback, dim3(B_DIM * N_DIM * N_DIM), dim3(64), 0, stream,
                           s, t, out);
    }
}